// Round 1
// 114.048 us; speedup vs baseline: 1.0335x; 1.0335x over previous
//
#include <hip/hip_runtime.h>

// y: [B=8, C=192, H=64, W=64] f32; codebooks: [G=8, K=512, d=24] f32
// out (f32, concat): universal_ctx | y_ba | code_index [B,1,G,H,W]
// d_ws: >= 256 KiB scratch; holds 8 precomputed 26 KiB codebook images.
#define B_   8
#define C_   192
#define HW_  4096
#define G_   8
#define K_   512
#define D_   24
#define CBSZ (K_ * D_)
#define THREADS 256

// Per-group image, halfword units:
//   frag region: 32 tiles * 384 hw = 12288 hw (24576 B) -- bf16-hi code fragments
//   e2 region:   512 f32 (2048 B) of (256.0 + ||e_n||^2), exact f32, pre-biased
#define FRAG_HW   12288
#define IMG_HW    13312          // 26624 B per group
#define LDS_BYTES 26624
#define TILES_PER_GROUP 2048     // B*HW/16 per group
#define WAVES_PER_GROUP 768      // 192 blocks * 4 waves

typedef float  f32x4 __attribute__((ext_vector_type(4)));
typedef int    i32x4 __attribute__((ext_vector_type(4)));
typedef short  s16x8 __attribute__((ext_vector_type(8)));
typedef short  s16x4 __attribute__((ext_vector_type(4)));
typedef unsigned long long u64;

static __device__ __forceinline__ unsigned umin_(unsigned a, unsigned b){return a<b?a:b;}
static __device__ __forceinline__ unsigned umax_(unsigned a, unsigned b){return a>b?a:b;}
static __device__ __forceinline__ unsigned short f2bf(float x){       // RNE f32->bf16
    unsigned u=__float_as_uint(x);
    return (unsigned short)((u + 0x7FFFu + ((u>>16)&1u))>>16);
}

// ---------- pre-kernel: build per-group 26 KiB images in ws ----------
// frag: idx = t*384 + lane*8 + j, lane = (k>>3)*16 + (n&15) in [0,48), j = k&7
// e2:   float at (img + FRAG_HW), entry n = 256.0 + ||e_n||^2  (exact f32)
__global__ __launch_bounds__(THREADS) void vq_stage(
    const float* __restrict__ cb, unsigned short* __restrict__ ws)
{
    const int g = blockIdx.x >> 3;
    const int s = blockIdx.x & 7;              // 64-code slice of this group
    const int tid = threadIdx.x;
    const float* cbg = cb + g * CBSZ;
    unsigned short* img = ws + g * IMG_HW;

    // fragment part: this slice covers float4 indices [s*384, s*384+384)
    for (int i = tid; i < 384; i += THREADS) {
        int gi = s * 384 + i;
        f32x4 v = ((const f32x4*)cbg)[gi];
        int i4 = gi << 2;
        int n  = i4 / 24;                      // float4 never crosses a row
        int k0 = i4 - n * 24;
        int off = (n >> 4) * 384 + (((k0 >> 3) << 4) + (n & 15)) * 8 + (k0 & 7);
        s16x4 h;
        h[0]=(short)f2bf(v[0]); h[1]=(short)f2bf(v[1]);
        h[2]=(short)f2bf(v[2]); h[3]=(short)f2bf(v[3]);
        *(s16x4*)(&img[off]) = h;              // 8B-aligned (k0&7 in {0,4})
    }
    // e2 table (biased by +256), one f32 per code
    if (tid < 64) {
        int n = s * 64 + tid;
        const float* row = cbg + n * D_;
        double s0 = 0.0, s1 = 0.0;
        #pragma unroll
        for (int j = 0; j < D_; j += 2) {
            double v0 = (double)row[j], v1 = (double)row[j+1];
            s0 = fma(v0,v0,s0); s1 = fma(v1,v1,s1);
        }
        ((float*)(img + FRAG_HW))[n] = (float)(256.0 + s0 + s1);
    }
}

// ------------------------------- main kernel ---------------------------------
__global__ __launch_bounds__(THREADS, 6) void vq_mfma6(
    const float* __restrict__ y, const float* __restrict__ cb,
    const unsigned short* __restrict__ ws, float* __restrict__ out)
{
    __shared__ __align__(16) unsigned short sB[IMG_HW];   // 26624 B -> 6 blocks/CU

    const int bid = blockIdx.x;
    const int g = bid & 7;
    const int blkg = bid >> 3;                 // 192 blocks per group
    const int tid = threadIdx.x;
    const int wave = tid >> 6, lane = tid & 63;
    const int c = lane & 15, q = lane >> 4;

    const float* cbg = cb + g * CBSZ;

    // ---- staging = straight 26624 B copy of the precomputed image ----
    {
        const char* src = (const char*)(ws + g * IMG_HW);
        char* dst = (char*)sB;
        #pragma unroll
        for (int it = 0; it < 7; ++it) {
            int off = it * 4096 + tid * 16;
            if (off < LDS_BYTES)
                *(i32x4*)(dst + off) = *(const i32x4*)(src + off);
        }
    }
    __syncthreads();

    float* out0 = out;
    float* out1 = out + B_*C_*HW_;
    float* out2 = out + 2*B_*C_*HW_;

    // A-fragment pointer: lanes 48..63 alias lanes 0..15 (finite data; their
    // k=24..31 products multiply a zero B operand, contributing nothing).
    const unsigned short* aptr = sB + (lane < 48 ? lane : lane - 48) * 8;
    // e2 accumulator-init pointer: lane (c,q) reg r -> code t*16 + q*4 + r
    const f32x4* e2p = (const f32x4*)((const float*)(sB + FRAG_HW) + (q << 2));

    const int wsid = (blkg << 2) + wave;       // wave slot within group [0,768)

    for (int tt = wsid; tt < TILES_PER_GROUP; tt += WAVES_PER_GROUP) {
        const int bimg = tt >> 8;
        const int hw   = (tt & 255) << 4;
        const int ybase = (bimg*C_ + g*D_)*HW_ + hw;
        const float* yb = y + ybase;

        // ---- B operand: lane (c,q<3) holds (-2x)[pos c][k=q*8+j]; q==3 -> 0 ----
        float xf[8];
        unsigned hx[4], lx[4];
        if (q < 3) {
            const float* yq = yb + (q*8)*HW_ + c;
            #pragma unroll
            for (int jj = 0; jj < 8; ++jj) xf[jj] = -2.0f * yq[jj*HW_];
            #pragma unroll
            for (int p2 = 0; p2 < 4; ++p2) {
                float f0 = xf[2*p2], f1 = xf[2*p2+1];
                unsigned u0 = __float_as_uint(f0), u1v = __float_as_uint(f1);
                hx[p2] = (u1v & 0xFFFF0000u) | (u0 >> 16);        // trunc-hi pair
                float l0 = f0 - __uint_as_float(u0 & 0xFFFF0000u);
                float l1 = f1 - __uint_as_float(u1v & 0xFFFF0000u);
                lx[p2] = (unsigned)f2bf(l0) | ((unsigned)f2bf(l1) << 16);
            }
        } else {
            #pragma unroll
            for (int jj = 0; jj < 8; ++jj) xf[jj] = 0.0f;
            hx[0]=0u; hx[1]=0u; hx[2]=0u; hx[3]=0u;
            lx[0]=0u; lx[1]=0u; lx[2]=0u; lx[3]=0u;
        }
        const s16x8 Xh = __builtin_bit_cast(s16x8, (i32x4){(int)hx[0],(int)hx[1],(int)hx[2],(int)hx[3]});
        const s16x8 Xl = __builtin_bit_cast(s16x8, (i32x4){(int)lx[0],(int)lx[1],(int)lx[2],(int)lx[3]});

        // ---- screen: A=codes (LDS frags), B=x; acc init = 256 + ||e||^2 (exact).
        //      Per-lane top-3 via v_med3_u32 insertion (quant 2^-6, 9-bit id). ----
        unsigned b1=0xFFFFFFFFu, b2=0xFFFFFFFFu, b3=0xFFFFFFFFu;
        const unsigned qr4 = (unsigned)(q << 2);
        #pragma unroll 8
        for (int t = 0; t < 32; ++t) {
            s16x8 eh = *(const s16x8*)(aptr + t * 384);
            f32x4 acc = e2p[t * 4];            // broadcast ds_read_b128
            acc = __builtin_amdgcn_mfma_f32_16x16x32_bf16(eh, Xh, acc, 0,0,0);
            acc = __builtin_amdgcn_mfma_f32_16x16x32_bf16(eh, Xl, acc, 0,0,0);
            const unsigned cbase = ((unsigned)t << 4) + qr4;
            #pragma unroll
            for (int r = 0; r < 4; ++r) {
                unsigned key = (__float_as_uint(acc[r]) & 0xFFFFFE00u) + (cbase + r);
                unsigned t3, t2;
                // invariant b1<=b2<=b3:  min(max(key,b2),b3) == med3(key,b2,b3)
                asm("v_med3_u32 %0, %1, %2, %3" : "=v"(t3) : "v"(key), "v"(b2), "v"(b3));
                asm("v_med3_u32 %0, %1, %2, %3" : "=v"(t2) : "v"(key), "v"(b1), "v"(b2));
                b3 = t3; b2 = t2;
                b1 = umin_(b1, key);
            }
        }

        // ---- 2-step butterfly (xor 16, 32): global top-3 for pos c ----
        #pragma unroll
        for (int d = 16; d < 64; d <<= 1) {
            unsigned o1=__shfl_xor(b1,d,64), o2=__shfl_xor(b2,d,64), o3=__shfl_xor(b3,d,64);
            unsigned x = umax_(b1,o1);
            unsigned yv= umin_(b2,o2);
            unsigned w = umax_(b2,o2);
            unsigned z = umin_(b3,o3);
            b1 = umin_(b1,o1);
            b2 = umin_(x,yv);
            b3 = umin_(umax_(x,yv), umin_(w,z));
        }

        // ---- gap-gated exact fp64 recheck (register partials, no y reload) ----
        const float v1 = __uint_as_float(b1 & 0xFFFFFE00u);
        const float v2 = __uint_as_float(b2 & 0xFFFFFE00u);
        int kwin;
        if (__ballot((v2 - v1) < 0.20f) == 0ull) {
            kwin = (int)(b1 & 511u);
        } else {
            double xd[8];
            #pragma unroll
            for (int jj = 0; jj < 8; ++jj) xd[jj] = (double)xf[jj];
            const unsigned cands[3] = {b1, b2, b3};
            u64 bestk = ~0ull;
            #pragma unroll
            for (int ci = 0; ci < 3; ++ci) {
                int kc = (int)(cands[ci] & 511u);
                double s = 0.0;
                if (q < 3) {
                    const f32x4* ce4 = (const f32x4*)(cbg + kc*D_ + (q<<3));
                    float ef[8];
                    *(f32x4*)&ef[0] = ce4[0];
                    *(f32x4*)&ef[4] = ce4[1];
                    #pragma unroll
                    for (int jj = 0; jj < 8; ++jj) {
                        double ev = (double)ef[jj];
                        s = fma(ev, ev, s);
                        s = fma(xd[jj], ev, s);
                    }
                }
                s += __shfl_xor(s, 16, 64);
                s += __shfl_xor(s, 32, 64);
                s += 256.0;
                u64 kk = (((u64)__double_as_longlong(s)) & ~0x1FFull) | (u64)kc;
                bestk = kk < bestk ? kk : bestk;
            }
            kwin = (int)(bestk & 511ull);
        }

        // ---- epilogue: lane (c,q<3) writes dims q*8..q*8+7 of pos c ----
        const float* cw = cbg + kwin * D_;
        if (q < 3) {
            const f32x4* cw4 = (const f32x4*)(cw + (q<<3));
            float v[8];
            *(f32x4*)&v[0] = cw4[0];
            *(f32x4*)&v[4] = cw4[1];
            const int ob = ybase + (q*8)*HW_ + c;
            #pragma unroll
            for (int jj = 0; jj < 8; ++jj) {
                out0[ob + jj*HW_] = v[jj];
                out1[ob + jj*HW_] = v[jj];
            }
        }
        if (lane < 16)
            out2[(bimg*G_ + g)*HW_ + hw + lane] = (float)kwin;
    }
}

extern "C" void kernel_launch(void* const* d_in, const int* in_sizes, int n_in,
                              void* d_out, int out_size, void* d_ws, size_t ws_size,
                              hipStream_t stream) {
    const float* y  = (const float*)d_in[0];
    const float* cb = (const float*)d_in[1];
    float* out = (float*)d_out;
    unsigned short* ws = (unsigned short*)d_ws;   // needs 8*26624 B = 208 KiB

    vq_stage<<<dim3(64), dim3(THREADS), 0, stream>>>(cb, ws);
    const int nblocks = 192 * G_;                 // 6 blocks/CU * 256 CU, one round
    vq_mfma6<<<dim3(nblocks), dim3(THREADS), 0, stream>>>(y, cb, ws, out);
}

// Round 2
// 112.726 us; speedup vs baseline: 1.0456x; 1.0117x over previous
//
#include <hip/hip_runtime.h>

// y: [B=8, C=192, H=64, W=64] f32; codebooks: [G=8, K=512, d=24] f32
// out (f32, concat): universal_ctx | y_ba | code_index [B,1,G,H,W]
// Single fused kernel: each block builds its group's 26 KiB LDS image from cb,
// then screens 2 position-tiles per wave. Grid = 1024 = 4 blocks/CU exactly.
#define B_   8
#define C_   192
#define HW_  4096
#define G_   8
#define K_   512
#define D_   24
#define CBSZ (K_ * D_)
#define THREADS 512              // 8 waves/block
#define NBLOCKS 1024             // 4 blocks/CU * 256 CU, one fully-resident round

// Per-group LDS image, halfword units:
//   frag region: 32 tiles * 384 hw = 12288 hw (24576 B) -- bf16-hi code fragments
//   e2 region:   512 f32 (2048 B) of (256.0 + ||e_n||^2), exact f32, pre-biased
#define FRAG_HW   12288
#define IMG_HW    13312          // 26624 B per block -> 4 blocks/CU by LDS, 32 waves/CU
#define TILES_PER_GROUP 2048     // B*HW/16 per group
#define WAVES_PER_GROUP 1024     // 128 blocks * 8 waves -> exactly 2 tiles/wave

typedef float  f32x4 __attribute__((ext_vector_type(4)));
typedef int    i32x4 __attribute__((ext_vector_type(4)));
typedef short  s16x8 __attribute__((ext_vector_type(8)));
typedef short  s16x4 __attribute__((ext_vector_type(4)));
typedef unsigned long long u64;

static __device__ __forceinline__ unsigned umin_(unsigned a, unsigned b){return a<b?a:b;}
static __device__ __forceinline__ unsigned umax_(unsigned a, unsigned b){return a>b?a:b;}
static __device__ __forceinline__ unsigned short f2bf(float x){       // RNE f32->bf16
    unsigned u=__float_as_uint(x);
    return (unsigned short)((u + 0x7FFFu + ((u>>16)&1u))>>16);
}

// ------------------------------- fused kernel --------------------------------
__global__ __launch_bounds__(THREADS, 8) void vq_mfma7(
    const float* __restrict__ y, const float* __restrict__ cb,
    float* __restrict__ out)
{
    __shared__ __align__(16) unsigned short sB[IMG_HW];   // 26624 B

    const int bid = blockIdx.x;
    const int g = bid & 7;                     // all blocks of a group share an XCD
    const int blkg = bid >> 3;                 // 128 blocks per group
    const int tid = threadIdx.x;
    const int wave = tid >> 6, lane = tid & 63;
    const int c = lane & 15, q = lane >> 4;

    const float* cbg = cb + g * CBSZ;

    // ---- fused staging: build bf16 fragment image from cb (L2-resident) ----
    // frag: idx = t*384 + lane8, lane8 = ((k>>3)*16 + (n&15))*8 + (k&7)
    #pragma unroll
    for (int it = 0; it < 6; ++it) {
        int gi = it * THREADS + tid;           // 3072 float4s cover the group
        f32x4 v = ((const f32x4*)cbg)[gi];
        int i4 = gi << 2;
        int n  = i4 / 24;                      // float4 never crosses a row
        int k0 = i4 - n * 24;
        int off = (n >> 4) * 384 + (((k0 >> 3) << 4) + (n & 15)) * 8 + (k0 & 7);
        s16x4 h;
        h[0]=(short)f2bf(v[0]); h[1]=(short)f2bf(v[1]);
        h[2]=(short)f2bf(v[2]); h[3]=(short)f2bf(v[3]);
        *(s16x4*)(&sB[off]) = h;               // 8B-aligned (k0&7 in {0,4})
    }
    // e2 table (biased by +256), exact f32, one code per thread
    {
        const int n = tid;                     // 512 threads == 512 codes
        const float* row = cbg + n * D_;
        double s0 = 0.0, s1 = 0.0;
        #pragma unroll
        for (int j = 0; j < D_; j += 2) {
            double v0 = (double)row[j], v1 = (double)row[j+1];
            s0 = fma(v0,v0,s0); s1 = fma(v1,v1,s1);
        }
        ((float*)(sB + FRAG_HW))[n] = (float)(256.0 + s0 + s1);
    }
    __syncthreads();

    float* out0 = out;
    float* out1 = out + B_*C_*HW_;
    float* out2 = out + 2*B_*C_*HW_;

    // A-fragment pointer: lanes 48..63 alias lanes 0..15 (finite data; their
    // k=24..31 products multiply a zero B operand, contributing nothing).
    const unsigned short* aptr = sB + (lane < 48 ? lane : lane - 48) * 8;
    // e2 accumulator-init pointer: lane (c,q) reg r -> code t*16 + q*4 + r
    const f32x4* e2p = (const f32x4*)((const float*)(sB + FRAG_HW) + (q << 2));

    const int wsid = (blkg << 3) + wave;       // wave slot within group [0,1024)

    for (int tt = wsid; tt < TILES_PER_GROUP; tt += WAVES_PER_GROUP) {
        const int bimg = tt >> 8;
        const int hw   = (tt & 255) << 4;
        const int ybase = (bimg*C_ + g*D_)*HW_ + hw;
        const float* yb = y + ybase;

        // ---- B operand: lane (c,q<3) holds (-2x)[pos c][k=q*8+j]; q==3 -> 0 ----
        float xf[8];
        unsigned hx[4], lx[4];
        if (q < 3) {
            const float* yq = yb + (q*8)*HW_ + c;
            #pragma unroll
            for (int jj = 0; jj < 8; ++jj) xf[jj] = -2.0f * yq[jj*HW_];
            #pragma unroll
            for (int p2 = 0; p2 < 4; ++p2) {
                float f0 = xf[2*p2], f1 = xf[2*p2+1];
                unsigned u0 = __float_as_uint(f0), u1v = __float_as_uint(f1);
                hx[p2] = (u1v & 0xFFFF0000u) | (u0 >> 16);        // trunc-hi pair
                float l0 = f0 - __uint_as_float(u0 & 0xFFFF0000u);
                float l1 = f1 - __uint_as_float(u1v & 0xFFFF0000u);
                lx[p2] = (unsigned)f2bf(l0) | ((unsigned)f2bf(l1) << 16);
            }
        } else {
            #pragma unroll
            for (int jj = 0; jj < 8; ++jj) xf[jj] = 0.0f;
            hx[0]=0u; hx[1]=0u; hx[2]=0u; hx[3]=0u;
            lx[0]=0u; lx[1]=0u; lx[2]=0u; lx[3]=0u;
        }
        const s16x8 Xh = __builtin_bit_cast(s16x8, (i32x4){(int)hx[0],(int)hx[1],(int)hx[2],(int)hx[3]});
        const s16x8 Xl = __builtin_bit_cast(s16x8, (i32x4){(int)lx[0],(int)lx[1],(int)lx[2],(int)lx[3]});

        // ---- screen: A=codes (LDS frags), B=x; acc init = 256 + ||e||^2 (exact).
        //      Per-lane top-3 via v_med3_u32 insertion (quant 2^-6, 9-bit id). ----
        unsigned b1=0xFFFFFFFFu, b2=0xFFFFFFFFu, b3=0xFFFFFFFFu;
        const unsigned qr4 = (unsigned)(q << 2);
        #pragma unroll 8
        for (int t = 0; t < 32; ++t) {
            s16x8 eh = *(const s16x8*)(aptr + t * 384);
            f32x4 acc = e2p[t * 4];            // broadcast ds_read_b128
            acc = __builtin_amdgcn_mfma_f32_16x16x32_bf16(eh, Xh, acc, 0,0,0);
            acc = __builtin_amdgcn_mfma_f32_16x16x32_bf16(eh, Xl, acc, 0,0,0);
            const unsigned cbase = ((unsigned)t << 4) + qr4;
            #pragma unroll
            for (int r = 0; r < 4; ++r) {
                unsigned key = (__float_as_uint(acc[r]) & 0xFFFFFE00u) + (cbase + r);
                unsigned t3, t2;
                // invariant b1<=b2<=b3:  min(max(key,b2),b3) == med3(key,b2,b3)
                asm("v_med3_u32 %0, %1, %2, %3" : "=v"(t3) : "v"(key), "v"(b2), "v"(b3));
                asm("v_med3_u32 %0, %1, %2, %3" : "=v"(t2) : "v"(key), "v"(b1), "v"(b2));
                b3 = t3; b2 = t2;
                b1 = umin_(b1, key);
            }
        }

        // ---- 2-step butterfly (xor 16, 32): global top-3 for pos c ----
        #pragma unroll
        for (int d = 16; d < 64; d <<= 1) {
            unsigned o1=__shfl_xor(b1,d,64), o2=__shfl_xor(b2,d,64), o3=__shfl_xor(b3,d,64);
            unsigned x = umax_(b1,o1);
            unsigned yv= umin_(b2,o2);
            unsigned w = umax_(b2,o2);
            unsigned z = umin_(b3,o3);
            b1 = umin_(b1,o1);
            b2 = umin_(x,yv);
            b3 = umin_(umax_(x,yv), umin_(w,z));
        }

        // ---- gap-gated exact fp64 recheck (register partials, no y reload) ----
        const float v1 = __uint_as_float(b1 & 0xFFFFFE00u);
        const float v2 = __uint_as_float(b2 & 0xFFFFFE00u);
        int kwin;
        if (__ballot((v2 - v1) < 0.20f) == 0ull) {
            kwin = (int)(b1 & 511u);
        } else {
            double xd[8];
            #pragma unroll
            for (int jj = 0; jj < 8; ++jj) xd[jj] = (double)xf[jj];
            const unsigned cands[3] = {b1, b2, b3};
            u64 bestk = ~0ull;
            #pragma unroll
            for (int ci = 0; ci < 3; ++ci) {
                int kc = (int)(cands[ci] & 511u);
                double s = 0.0;
                if (q < 3) {
                    const f32x4* ce4 = (const f32x4*)(cbg + kc*D_ + (q<<3));
                    float ef[8];
                    *(f32x4*)&ef[0] = ce4[0];
                    *(f32x4*)&ef[4] = ce4[1];
                    #pragma unroll
                    for (int jj = 0; jj < 8; ++jj) {
                        double ev = (double)ef[jj];
                        s = fma(ev, ev, s);
                        s = fma(xd[jj], ev, s);
                    }
                }
                s += __shfl_xor(s, 16, 64);
                s += __shfl_xor(s, 32, 64);
                s += 256.0;
                u64 kk = (((u64)__double_as_longlong(s)) & ~0x1FFull) | (u64)kc;
                bestk = kk < bestk ? kk : bestk;
            }
            kwin = (int)(bestk & 511ull);
        }

        // ---- epilogue: lane (c,q<3) writes dims q*8..q*8+7 of pos c ----
        const float* cw = cbg + kwin * D_;
        if (q < 3) {
            const f32x4* cw4 = (const f32x4*)(cw + (q<<3));
            float v[8];
            *(f32x4*)&v[0] = cw4[0];
            *(f32x4*)&v[4] = cw4[1];
            const int ob = ybase + (q*8)*HW_ + c;
            #pragma unroll
            for (int jj = 0; jj < 8; ++jj) {
                out0[ob + jj*HW_] = v[jj];
                out1[ob + jj*HW_] = v[jj];
            }
        }
        if (lane < 16)
            out2[(bimg*G_ + g)*HW_ + hw + lane] = (float)kwin;
    }
}

extern "C" void kernel_launch(void* const* d_in, const int* in_sizes, int n_in,
                              void* d_out, int out_size, void* d_ws, size_t ws_size,
                              hipStream_t stream) {
    const float* y  = (const float*)d_in[0];
    const float* cb = (const float*)d_in[1];
    float* out = (float*)d_out;
    (void)d_ws; (void)ws_size;                 // staging is fused; ws unused

    vq_mfma7<<<dim3(NBLOCKS), dim3(THREADS), 0, stream>>>(y, cb, out);
}